// Round 11
// baseline (156.306 us; speedup 1.0000x reference)
//
#include <hip/hip_runtime.h>
#include <hip/hip_bf16.h>

#define V_ 32000
#define E_ 100
#define H_ 128
#define B_ 1024
#define T_ 256

typedef float f32x4 __attribute__((ext_vector_type(4)));
typedef int   i32x4 __attribute__((ext_vector_type(4)));
typedef __bf16 bf16x8 __attribute__((ext_vector_type(8)));
typedef __bf16 bf16x4 __attribute__((ext_vector_type(4)));

__device__ __forceinline__ f32x4 mfma16(bf16x8 a, bf16x8 b, f32x4 c) {
    return __builtin_amdgcn_mfma_f32_16x16x32_bf16(a, b, c, 0, 0, 0);
}

// ---------------------------------------------------------------------------
// K0: pp[v][h] = bf16( emb[v,:] @ W_ih^T + b_ih + b_hh )  (K = 100, f32 acc)
// Input projection depends only on vocab id -> precompute once for all ids.
// grid 500 x 512thr; block covers 64 vocab; 8 waves = 4 v-tiles x 2 h-halves.
// ---------------------------------------------------------------------------
__global__ __launch_bounds__(512, 1) void k0_pp(
    const float* __restrict__ emb, const float* __restrict__ Wih,
    const float* __restrict__ bih, const float* __restrict__ bhh,
    __bf16* __restrict__ pp)
{
    const int tid = threadIdx.x;
    const int lane = tid & 63, w = tid >> 6;
    const int nt = w >> 1;               // vocab tile 0..3
    const int mh = w & 1;                // h half 0..1 (4 m-tiles each)
    const int v0 = blockIdx.x * 64;
    const int sub = lane >> 4, rc = lane & 15;
    const f32x4 z = {0.f, 0.f, 0.f, 0.f};

    bf16x8 af[4][4];
#pragma unroll
    for (int m = 0; m < 4; ++m)
#pragma unroll
        for (int kc = 0; kc < 4; ++kc) {
            int row = (mh * 4 + m) * 16 + rc;
            int k0 = kc * 32 + sub * 8;
            const float* s = Wih + (size_t)row * E_ + k0;
            f32x4 p0 = (k0 + 4 <= E_) ? *(const f32x4*)s : z;
            f32x4 p1 = (k0 + 8 <= E_) ? *(const f32x4*)(s + 4) : z;
            bf16x8 h8;
#pragma unroll
            for (int e = 0; e < 4; ++e) {
                h8[e] = (__bf16)p0[e];
                h8[4 + e] = (__bf16)p1[e];
            }
            af[m][kc] = h8;
        }

    bf16x8 bf[4];
#pragma unroll
    for (int kc = 0; kc < 4; ++kc) {
        int vrow = v0 + nt * 16 + rc;
        int k0 = kc * 32 + sub * 8;
        const float* s = emb + (size_t)vrow * E_ + k0;
        f32x4 p0 = (k0 + 4 <= E_) ? *(const f32x4*)s : z;
        f32x4 p1 = (k0 + 8 <= E_) ? *(const f32x4*)(s + 4) : z;
        bf16x8 h8;
#pragma unroll
        for (int e = 0; e < 4; ++e) {
            h8[e] = (__bf16)p0[e];
            h8[4 + e] = (__bf16)p1[e];
        }
        bf[kc] = h8;
    }

    f32x4 acc[4];
#pragma unroll
    for (int m = 0; m < 4; ++m) {
        int h0 = (mh * 4 + m) * 16 + sub * 4;
        acc[m] = *(const f32x4*)&bih[h0] + *(const f32x4*)&bhh[h0];
    }
#pragma unroll
    for (int kc = 0; kc < 4; ++kc)
#pragma unroll
        for (int m = 0; m < 4; ++m)
            acc[m] = mfma16(af[m][kc], bf[kc], acc[m]);

#pragma unroll
    for (int m = 0; m < 4; ++m) {
        int v = v0 + nt * 16 + rc;
        int h0 = (mh * 4 + m) * 16 + sub * 4;
        bf16x4 o;
#pragma unroll
        for (int r = 0; r < 4; ++r) o[r] = (__bf16)acc[m][r];
        *(bf16x4*)&pp[(size_t)v * H_ + h0] = o;
    }
}

// ---------------------------------------------------------------------------
// K2: RNN scan. 64 blocks x 16 batch; 8 waves (2/SIMD); wave w owns hidden
// rows [16w,16w+16). xt delivery: waves 0-3 issue ONE global_load_lds (16B)
// per step, cooperatively DMA-ing the 16 pp rows for step t+3 into a 4-slot
// LDS ring in granule layout (linear lane*16B DMA dest == granule order via
// pre-swizzled per-lane global source). Counted vmcnt(2/3) keeps DMAs in
// flight across barriers; slot(t+3) vs read(t) disjoint mod 4. Consumers
// read xt via 1 ds_read_b64 joining the existing lgkm wait. No per-lane
// gathers, no index math on consumer waves. 1 barrier/step.
// ---------------------------------------------------------------------------
__global__ __launch_bounds__(512, 1) void k2_rnn(
    const int* __restrict__ x, const __bf16* __restrict__ pp,
    const float* __restrict__ Whh, __bf16* __restrict__ hg)
{
    __shared__ __align__(16) __bf16 Hg[2][2048];
    __shared__ __align__(16) __bf16 Hx[4][2048];   // xt ring, granule layout
    const int tid = threadIdx.x;
    const int lane = tid & 63, w = tid >> 6;
    const int bi = blockIdx.x;
    const int b0 = bi * 16;
    const int sub = lane >> 4, c = lane & 15;

    // A fragments: W_hh rows w*16 + c (bf16); loop-invariant
    bf16x8 wah[4];
#pragma unroll
    for (int kc = 0; kc < 4; ++kc) {
        const float* src = Whh + (size_t)(w * 16 + c) * H_ + kc * 32 + sub * 8;
        f32x4 p0 = *(const f32x4*)src, p1 = *(const f32x4*)(src + 4);
        bf16x8 h8;
#pragma unroll
        for (int e = 0; e < 4; ++e) {
            h8[e] = (__bf16)p0[e];
            h8[4 + e] = (__bf16)p1[e];
        }
        wah[kc] = h8;
    }

    if (tid < 256) {
        bf16x8 z8;
#pragma unroll
        for (int e = 0; e < 8; ++e) z8[e] = (__bf16)0.0f;
        *(bf16x8*)&Hg[0][tid * 8] = z8;
    }

    const int i0 = w * 16 + sub * 4;            // this lane's 4 hidden-out rows
    const int* xrow = x + (size_t)(b0 + c) * T_; // per-lane idx row (c = lane&15)
    // staging lane's element offset within a pp row (granule decode of
    // lds elem off8 = w*64 + lane): i_base = w*32 + ((lane>>4)&3)*8
    const int sk = w * 32 + ((lane >> 4) & 3) * 8;

    // LDS elem-offset for (rows i0..i0+3, col c) in granule layout; used for
    // the h write AND the xt slot read (same layout).
    const int wb = (((w >> 1) * 64 + ((w & 1) * 2 + (sub >> 1)) * 16 + c) << 3)
                 + (sub & 1) * 4;

    bf16x4 h4;                                   // last-written h (for hg)

#define DMA(XV, SLOT)                                                        \
    do { if (w < 4) {                                                        \
        const __bf16* gsrc = pp + (size_t)(XV) * H_ + sk;                    \
        __builtin_amdgcn_global_load_lds(gsrc, &Hx[SLOT][w * 512], 16, 0, 0);\
    } } while (0)

#define K2_STEP(PK, SK, VMS, STAGE) do {                                    \
        const __bf16* Hp = &Hg[PK][0];                                      \
        bf16x8 hb0 = *(const bf16x8*)(Hp + lane * 8);                       \
        bf16x8 hb1 = *(const bf16x8*)(Hp + 512 + lane * 8);                 \
        bf16x8 hb2 = *(const bf16x8*)(Hp + 1024 + lane * 8);                \
        bf16x8 hb3 = *(const bf16x8*)(Hp + 1536 + lane * 8);                \
        bf16x4 xtv = *(const bf16x4*)&Hx[SK][wb];                           \
        STAGE;                                                              \
        f32x4 xf;                                                           \
        _Pragma("unroll")                                                   \
        for (int r = 0; r < 4; ++r) xf[r] = (float)xtv[r];                  \
        f32x4 zz = {0.f, 0.f, 0.f, 0.f};                                    \
        f32x4 a0 = mfma16(wah[0], hb0, xf);                                 \
        f32x4 a1 = mfma16(wah[1], hb1, zz);                                 \
        a0 = mfma16(wah[2], hb2, a0);                                       \
        a1 = mfma16(wah[3], hb3, a1);                                       \
        f32x4 s = a0 + a1;                                                  \
        _Pragma("unroll")                                                   \
        for (int r = 0; r < 4; ++r) {                                       \
            float e;                                                        \
            asm("v_exp_f32 %0, %1" : "=v"(e) : "v"(s[r] * 2.8853900817779268f)); \
            float ep1 = e + 1.0f;                                           \
            float rcp;                                                      \
            asm("v_rcp_f32 %0, %1" : "=v"(rcp) : "v"(ep1));                 \
            h4[r] = (__bf16)(1.0f - 2.0f * rcp);                            \
        }                                                                   \
        *(bf16x4*)&Hg[(PK) ^ 1][wb] = h4;                                   \
        asm volatile("s_waitcnt vmcnt(" VMS ") lgkmcnt(0)" ::: "memory");   \
        __builtin_amdgcn_s_barrier();                                       \
        __builtin_amdgcn_sched_barrier(0);                                  \
    } while (0)

    // prologue: stage slots 0..2 (t = 0..2); preload idx for t 0..7
    i32x4 xs0, xs1;
    if (w < 4) {
        xs0 = *(const i32x4*)(xrow);
        DMA(xs0[0], 0);
        DMA(xs0[1], 1);
        DMA(xs0[2], 2);
        xs1 = *(const i32x4*)(xrow + 4);
    }
    __syncthreads();   // drains prologue DMAs (vmcnt 0) + covers Hg init

    for (int j = 0; j < T_ / 4; ++j) {
        // idx pointer for group j+2, clamped at tail (values unused there)
        const int* xnext = xrow + ((4 * (j + 2) <= T_ - 4) ? 4 * (j + 2) : (T_ - 4));
        i32x4 xs2;
        K2_STEP(0, 0, "2", { DMA(xs0[3], 3); });                   // t = 4j
        K2_STEP(1, 1, "2", { DMA(xs1[0], 0); });                   // t = 4j+1
        K2_STEP(0, 2, "2", { DMA(xs1[1], 1); });                   // t = 4j+2
        K2_STEP(1, 3, "3", { DMA(xs1[2], 2);
                             if (w < 4) xs2 = *(const i32x4*)(xnext); }); // t=4j+3
        if (w < 4) { xs0 = xs1; xs1 = xs2; }
    }
#undef K2_STEP
#undef DMA

    // final h of step T-1 -> hg granules for K3
    *(bf16x4*)&hg[(size_t)(bi >> 3) * 16384 + (size_t)(bi & 7) * 2048 + wb] = h4;
}

// ---------------------------------------------------------------------------
// K3: out[b][v] = h[b] @ W_fc[v]^T + b_fc[v]. One block per v-tile (gv);
// A-frags cvt'd from f32 Wfc ONCE, loop over all 8 batch-tiles. grid 250.
// ---------------------------------------------------------------------------
__global__ __launch_bounds__(512, 1) void k3_head(
    const float* __restrict__ Wfc, const __bf16* __restrict__ hg,
    const float* __restrict__ bfc, float* __restrict__ out)
{
    const int tid = threadIdx.x;
    const int lane = tid & 63, w = tid >> 6;
    const int gv = blockIdx.x;
    const int v0 = gv * 128;
    const int sub = lane >> 4, rc = lane & 15;
    const int mt0 = (w & 3) * 2, nt0 = (w >> 2) * 4;

    bf16x8 af[2][4];
#pragma unroll
    for (int m = 0; m < 2; ++m)
#pragma unroll
        for (int kc = 0; kc < 4; ++kc) {
            int row = v0 + (mt0 + m) * 16 + rc;
            const float* src = Wfc + (size_t)row * H_ + (kc * 4 + sub) * 8;
            f32x4 p0 = *(const f32x4*)src, p1 = *(const f32x4*)(src + 4);
            bf16x8 h8;
#pragma unroll
            for (int e = 0; e < 4; ++e) {
                h8[e] = (__bf16)p0[e];
                h8[4 + e] = (__bf16)p1[e];
            }
            af[m][kc] = h8;
        }

    f32x4 bias4[2];
#pragma unroll
    for (int m = 0; m < 2; ++m)
        bias4[m] = *(const f32x4*)&bfc[v0 + (mt0 + m) * 16 + sub * 4];

    for (int bt = 0; bt < 8; ++bt) {
        const int b0 = bt * 128;
        f32x4 acc[2][4];
#pragma unroll
        for (int m = 0; m < 2; ++m)
#pragma unroll
            for (int n = 0; n < 4; ++n) acc[m][n] = (f32x4){0.f, 0.f, 0.f, 0.f};

#pragma unroll
        for (int kc = 0; kc < 4; ++kc) {
            bf16x8 bf[4];
#pragma unroll
            for (int n = 0; n < 4; ++n)
                bf[n] = *(const bf16x8*)&hg[(size_t)bt * 16384
                          + (size_t)(((nt0 + n) * 256) + kc * 64 + lane) * 8];
#pragma unroll
            for (int n = 0; n < 4; ++n)
#pragma unroll
                for (int m = 0; m < 2; ++m)
                    acc[m][n] = mfma16(af[m][kc], bf[n], acc[m][n]);
        }
#pragma unroll
        for (int n = 0; n < 4; ++n)
#pragma unroll
            for (int m = 0; m < 2; ++m) {
                f32x4 v = acc[m][n] + bias4[m];
                float* dst = out + (size_t)(b0 + (nt0 + n) * 16 + rc) * V_
                                 + v0 + (mt0 + m) * 16 + sub * 4;
                *(f32x4*)dst = v;
            }
    }
}

extern "C" void kernel_launch(void* const* d_in, const int* in_sizes, int n_in,
                              void* d_out, int out_size, void* d_ws, size_t ws_size,
                              hipStream_t stream) {
    const int*   x   = (const int*)d_in[0];
    const float* emb = (const float*)d_in[1];
    const float* Wih = (const float*)d_in[2];
    const float* Whh = (const float*)d_in[3];
    const float* bih = (const float*)d_in[4];
    const float* bhh = (const float*)d_in[5];
    const float* Wfc = (const float*)d_in[6];
    const float* bfc = (const float*)d_in[7];
    float* out = (float*)d_out;

    const size_t SZ_HG = 262144;                    // 8 x 16384 bf16
    const size_t SZ_PP = (size_t)V_ * H_ * 2;       // 8.192 MB

    char* wsb = (char*)d_ws;
    size_t off = 0;
    auto take = [&](size_t n) -> char* {
        char* p = wsb + off;
        off += (n + 255) & ~(size_t)255;
        return p;
    };
    auto fits = [&](size_t n) { return off + n + 256 <= ws_size; };

    __bf16* hgp = (__bf16*)take(SZ_HG);             // required in ws
    // pp: prefer ws; fallback into d_out (k3 overwrites it only after k2 done)
    __bf16* pp = fits(SZ_PP) ? (__bf16*)take(SZ_PP) : (__bf16*)d_out;

    k0_pp<<<dim3(500), 512, 0, stream>>>(emb, Wih, bih, bhh, pp);
    k2_rnn<<<dim3(64), 512, 0, stream>>>(x, pp, Whh, hgp);
    k3_head<<<dim3(250), 512, 0, stream>>>(Wfc, hgp, bfc, out);
}

// Round 13
// 151.008 us; speedup vs baseline: 1.0351x; 1.0351x over previous
//
#include <hip/hip_runtime.h>
#include <hip/hip_bf16.h>

#define V_ 32000
#define E_ 100
#define H_ 128
#define B_ 1024
#define T_ 256

typedef float f32x4 __attribute__((ext_vector_type(4)));
typedef int   i32x4 __attribute__((ext_vector_type(4)));
typedef __bf16 bf16x8 __attribute__((ext_vector_type(8)));
typedef __bf16 bf16x4 __attribute__((ext_vector_type(4)));

__device__ __forceinline__ f32x4 mfma16(bf16x8 a, bf16x8 b, f32x4 c) {
    return __builtin_amdgcn_mfma_f32_16x16x32_bf16(a, b, c, 0, 0, 0);
}

// ---------------------------------------------------------------------------
// K0: pp[v][h] = bf16( emb[v,:] @ W_ih^T + b_ih + b_hh )  (K = 100, f32 acc)
// Input projection depends only on vocab id -> precompute once for all ids.
// grid 500 x 512thr; block covers 64 vocab; 8 waves = 4 v-tiles x 2 h-halves.
// ---------------------------------------------------------------------------
__global__ __launch_bounds__(512, 1) void k0_pp(
    const float* __restrict__ emb, const float* __restrict__ Wih,
    const float* __restrict__ bih, const float* __restrict__ bhh,
    __bf16* __restrict__ pp)
{
    const int tid = threadIdx.x;
    const int lane = tid & 63, w = tid >> 6;
    const int nt = w >> 1;               // vocab tile 0..3
    const int mh = w & 1;                // h half 0..1 (4 m-tiles each)
    const int v0 = blockIdx.x * 64;
    const int sub = lane >> 4, rc = lane & 15;
    const f32x4 z = {0.f, 0.f, 0.f, 0.f};

    bf16x8 af[4][4];
#pragma unroll
    for (int m = 0; m < 4; ++m)
#pragma unroll
        for (int kc = 0; kc < 4; ++kc) {
            int row = (mh * 4 + m) * 16 + rc;
            int k0 = kc * 32 + sub * 8;
            const float* s = Wih + (size_t)row * E_ + k0;
            f32x4 p0 = (k0 + 4 <= E_) ? *(const f32x4*)s : z;
            f32x4 p1 = (k0 + 8 <= E_) ? *(const f32x4*)(s + 4) : z;
            bf16x8 h8;
#pragma unroll
            for (int e = 0; e < 4; ++e) {
                h8[e] = (__bf16)p0[e];
                h8[4 + e] = (__bf16)p1[e];
            }
            af[m][kc] = h8;
        }

    bf16x8 bf[4];
#pragma unroll
    for (int kc = 0; kc < 4; ++kc) {
        int vrow = v0 + nt * 16 + rc;
        int k0 = kc * 32 + sub * 8;
        const float* s = emb + (size_t)vrow * E_ + k0;
        f32x4 p0 = (k0 + 4 <= E_) ? *(const f32x4*)s : z;
        f32x4 p1 = (k0 + 8 <= E_) ? *(const f32x4*)(s + 4) : z;
        bf16x8 h8;
#pragma unroll
        for (int e = 0; e < 4; ++e) {
            h8[e] = (__bf16)p0[e];
            h8[4 + e] = (__bf16)p1[e];
        }
        bf[kc] = h8;
    }

    f32x4 acc[4];
#pragma unroll
    for (int m = 0; m < 4; ++m) {
        int h0 = (mh * 4 + m) * 16 + sub * 4;
        acc[m] = *(const f32x4*)&bih[h0] + *(const f32x4*)&bhh[h0];
    }
#pragma unroll
    for (int kc = 0; kc < 4; ++kc)
#pragma unroll
        for (int m = 0; m < 4; ++m)
            acc[m] = mfma16(af[m][kc], bf[kc], acc[m]);

#pragma unroll
    for (int m = 0; m < 4; ++m) {
        int v = v0 + nt * 16 + rc;
        int h0 = (mh * 4 + m) * 16 + sub * 4;
        bf16x4 o;
#pragma unroll
        for (int r = 0; r < 4; ++r) o[r] = (__bf16)acc[m][r];
        *(bf16x4*)&pp[(size_t)v * H_ + h0] = o;
    }
}

// ---------------------------------------------------------------------------
// K1g: xpb[t][b][:] = pp[x[b,t]][:]  — pure gather-copy, massively parallel
// (latency-free regime, unlike inside k2's barrier-locked loop). One 16B
// chunk per thread; 16 chunks per 128-elem row (FIX: was 8 -> upper half of
// each row was never written). Writes perfectly coalesced.
// grid 16384 x 256 (T*B*16 chunks exactly).
// ---------------------------------------------------------------------------
__global__ __launch_bounds__(256, 4) void k1_gather(
    const int* __restrict__ x, const __bf16* __restrict__ pp,
    __bf16* __restrict__ xpb)
{
    size_t i = (size_t)blockIdx.x * 256 + threadIdx.x;   // chunk id
    size_t row = i >> 4;          // t*B + b   (16 chunks of 8 elems = 128)
    int k8 = (int)(i & 15) * 8;   // element offset of 16B chunk
    int t = (int)(row >> 10);     // B_ = 1024
    int b = (int)(row & 1023);
    int idx = x[(size_t)b * T_ + t];
    bf16x8 v = *(const bf16x8*)&pp[(size_t)idx * H_ + k8];
    *(bf16x8*)&xpb[row * H_ + k8] = v;
}

// ---------------------------------------------------------------------------
// K2: RNN scan — exact R8 structure (proven 82 µs). 64 blocks x 16 batch;
// 8 waves (2/SIMD); wave w owns hidden rows [16w,16w+16). Coalesced xpb
// streams with SGPR-uniform address increments; time loop unrolled x4 with
// position-named prefetch regs (counted vmcnt, loads in flight across
// barriers). Static LDS ping-pong; xt folded into MFMA C-init; 1 barrier/step.
// ---------------------------------------------------------------------------
__global__ __launch_bounds__(512, 1) void k2_rnn(
    const __bf16* __restrict__ xpb, const float* __restrict__ Whh,
    __bf16* __restrict__ hg)
{
    __shared__ __align__(16) __bf16 Hg[2][2048];
    const int tid = threadIdx.x;
    const int lane = tid & 63, w = tid >> 6;
    const int bi = blockIdx.x;
    const int b0 = bi * 16;
    const int sub = lane >> 4, c = lane & 15;

    // A fragments: W_hh rows w*16 + c (bf16); loop-invariant
    bf16x8 wah[4];
#pragma unroll
    for (int kc = 0; kc < 4; ++kc) {
        const float* src = Whh + (size_t)(w * 16 + c) * H_ + kc * 32 + sub * 8;
        f32x4 p0 = *(const f32x4*)src, p1 = *(const f32x4*)(src + 4);
        bf16x8 h8;
#pragma unroll
        for (int e = 0; e < 4; ++e) {
            h8[e] = (__bf16)p0[e];
            h8[4 + e] = (__bf16)p1[e];
        }
        wah[kc] = h8;
    }

    if (tid < 256) {
        bf16x8 z8;
#pragma unroll
        for (int e = 0; e < 8; ++e) z8[e] = (__bf16)0.0f;
        *(bf16x8*)&Hg[0][tid * 8] = z8;
    }
    __syncthreads();

    const int i0 = w * 16 + sub * 4;            // this lane's 4 hidden-out rows
    const __bf16* xq = xpb + (size_t)(b0 + c) * H_ + i0;
    const size_t xstep = (size_t)B_ * H_;

    // LDS write elem-offset for hidden rows i0..i0+3, col c (granule layout)
    const int wb = (((w >> 1) * 64 + ((w & 1) * 2 + (sub >> 1)) * 16 + c) << 3)
                 + (sub & 1) * 4;

    bf16x4 h4;                                   // last-written h (for hg)

#define K2_STEP(PK, XREG) do {                                              \
        const __bf16* Hp = &Hg[PK][0];                                      \
        bf16x8 hb0 = *(const bf16x8*)(Hp + lane * 8);                       \
        bf16x8 hb1 = *(const bf16x8*)(Hp + 512 + lane * 8);                 \
        bf16x8 hb2 = *(const bf16x8*)(Hp + 1024 + lane * 8);                \
        bf16x8 hb3 = *(const bf16x8*)(Hp + 1536 + lane * 8);                \
        f32x4 xf;                                                           \
        _Pragma("unroll")                                                   \
        for (int r = 0; r < 4; ++r) xf[r] = (float)XREG[r];                 \
        f32x4 zz = {0.f, 0.f, 0.f, 0.f};                                    \
        f32x4 a0 = mfma16(wah[0], hb0, xf);                                 \
        f32x4 a1 = mfma16(wah[1], hb1, zz);                                 \
        a0 = mfma16(wah[2], hb2, a0);                                       \
        a1 = mfma16(wah[3], hb3, a1);                                       \
        f32x4 s = a0 + a1;                                                  \
        _Pragma("unroll")                                                   \
        for (int r = 0; r < 4; ++r) {                                       \
            float e;                                                        \
            asm("v_exp_f32 %0, %1" : "=v"(e) : "v"(s[r] * 2.8853900817779268f)); \
            float ep1 = e + 1.0f;                                           \
            float rcp;                                                      \
            asm("v_rcp_f32 %0, %1" : "=v"(rcp) : "v"(ep1));                 \
            h4[r] = (__bf16)(1.0f - 2.0f * rcp);                            \
        }                                                                   \
        *(bf16x4*)&Hg[(PK) ^ 1][wb] = h4;                                   \
        asm volatile("s_waitcnt lgkmcnt(0)" ::: "memory");                  \
        __builtin_amdgcn_s_barrier();                                       \
        __builtin_amdgcn_sched_barrier(0);                                  \
    } while (0)

    // steps 0..3 prefetch (position-named, no rotation)
    bf16x4 xc0 = *(const bf16x4*)(xq);
    bf16x4 xc1 = *(const bf16x4*)(xq + xstep);
    bf16x4 xc2 = *(const bf16x4*)(xq + 2 * xstep);
    bf16x4 xc3 = *(const bf16x4*)(xq + 3 * xstep);
    xq += 4 * xstep;

    for (int j = 0; j < T_ / 4; ++j) {
        bf16x4 xn0, xn1, xn2, xn3;
        if (j < T_ / 4 - 1) {
            xn0 = *(const bf16x4*)(xq);
            xn1 = *(const bf16x4*)(xq + xstep);
            xn2 = *(const bf16x4*)(xq + 2 * xstep);
            xn3 = *(const bf16x4*)(xq + 3 * xstep);
            xq += 4 * xstep;
        }
        K2_STEP(0, xc0);
        K2_STEP(1, xc1);
        K2_STEP(0, xc2);
        K2_STEP(1, xc3);
        xc0 = xn0; xc1 = xn1; xc2 = xn2; xc3 = xn3;
    }
#undef K2_STEP

    // final h of step T-1 (in Hg[0] and h4) -> hg granules for K3
    *(bf16x4*)&hg[(size_t)(bi >> 3) * 16384 + (size_t)(bi & 7) * 2048 + wb] = h4;
}

// ---------------------------------------------------------------------------
// K3: out[b][v] = h[b] @ W_fc[v]^T + b_fc[v]. One block per v-tile (gv);
// A-frags cvt'd from f32 Wfc ONCE, loop over all 8 batch-tiles. grid 250.
// ---------------------------------------------------------------------------
__global__ __launch_bounds__(512, 1) void k3_head(
    const float* __restrict__ Wfc, const __bf16* __restrict__ hg,
    const float* __restrict__ bfc, float* __restrict__ out)
{
    const int tid = threadIdx.x;
    const int lane = tid & 63, w = tid >> 6;
    const int gv = blockIdx.x;
    const int v0 = gv * 128;
    const int sub = lane >> 4, rc = lane & 15;
    const int mt0 = (w & 3) * 2, nt0 = (w >> 2) * 4;

    bf16x8 af[2][4];
#pragma unroll
    for (int m = 0; m < 2; ++m)
#pragma unroll
        for (int kc = 0; kc < 4; ++kc) {
            int row = v0 + (mt0 + m) * 16 + rc;
            const float* src = Wfc + (size_t)row * H_ + (kc * 4 + sub) * 8;
            f32x4 p0 = *(const f32x4*)src, p1 = *(const f32x4*)(src + 4);
            bf16x8 h8;
#pragma unroll
            for (int e = 0; e < 4; ++e) {
                h8[e] = (__bf16)p0[e];
                h8[4 + e] = (__bf16)p1[e];
            }
            af[m][kc] = h8;
        }

    f32x4 bias4[2];
#pragma unroll
    for (int m = 0; m < 2; ++m)
        bias4[m] = *(const f32x4*)&bfc[v0 + (mt0 + m) * 16 + sub * 4];

    for (int bt = 0; bt < 8; ++bt) {
        const int b0 = bt * 128;
        f32x4 acc[2][4];
#pragma unroll
        for (int m = 0; m < 2; ++m)
#pragma unroll
            for (int n = 0; n < 4; ++n) acc[m][n] = (f32x4){0.f, 0.f, 0.f, 0.f};

#pragma unroll
        for (int kc = 0; kc < 4; ++kc) {
            bf16x8 bf[4];
#pragma unroll
            for (int n = 0; n < 4; ++n)
                bf[n] = *(const bf16x8*)&hg[(size_t)bt * 16384
                          + (size_t)(((nt0 + n) * 256) + kc * 64 + lane) * 8];
#pragma unroll
            for (int n = 0; n < 4; ++n)
#pragma unroll
                for (int m = 0; m < 2; ++m)
                    acc[m][n] = mfma16(af[m][kc], bf[n], acc[m][n]);
        }
#pragma unroll
        for (int n = 0; n < 4; ++n)
#pragma unroll
            for (int m = 0; m < 2; ++m) {
                f32x4 v = acc[m][n] + bias4[m];
                float* dst = out + (size_t)(b0 + (nt0 + n) * 16 + rc) * V_
                                 + v0 + (mt0 + m) * 16 + sub * 4;
                *(f32x4*)dst = v;
            }
    }
}

extern "C" void kernel_launch(void* const* d_in, const int* in_sizes, int n_in,
                              void* d_out, int out_size, void* d_ws, size_t ws_size,
                              hipStream_t stream) {
    const int*   x   = (const int*)d_in[0];
    const float* emb = (const float*)d_in[1];
    const float* Wih = (const float*)d_in[2];
    const float* Whh = (const float*)d_in[3];
    const float* bih = (const float*)d_in[4];
    const float* bhh = (const float*)d_in[5];
    const float* Wfc = (const float*)d_in[6];
    const float* bfc = (const float*)d_in[7];
    float* out = (float*)d_out;

    const size_t SZ_HG  = 262144;                    // 8 x 16384 bf16
    const size_t SZ_PP  = (size_t)V_ * H_ * 2;       // 8.192 MB
    const size_t SZ_XPB = (size_t)T_ * B_ * H_ * 2;  // 64 MB

    char* wsb = (char*)d_ws;
    size_t off = 0;
    auto take = [&](size_t n) -> char* {
        char* p = wsb + off;
        off += (n + 255) & ~(size_t)255;
        return p;
    };
    char* outb = (char*)d_out;
    size_t ooff = 0;
    auto takeOut = [&](size_t n) -> char* {
        char* p = outb + ooff;
        ooff += (n + 255) & ~(size_t)255;
        return p;
    };
    auto fits = [&](size_t n) { return off + n + 256 <= ws_size; };

    __bf16* hgp = (__bf16*)take(SZ_HG);              // required in ws
    // pp / xpb: prefer ws; fallback into d_out (k3 overwrites out only last)
    __bf16* pp  = fits(SZ_PP)  ? (__bf16*)take(SZ_PP)  : (__bf16*)takeOut(SZ_PP);
    __bf16* xpb = fits(SZ_XPB) ? (__bf16*)take(SZ_XPB) : (__bf16*)takeOut(SZ_XPB);

    k0_pp<<<dim3(500), 512, 0, stream>>>(emb, Wih, bih, bhh, pp);
    k1_gather<<<dim3(16384), 256, 0, stream>>>(x, pp, xpb);
    k2_rnn<<<dim3(64), 512, 0, stream>>>(xpb, Whh, hgp);
    k3_head<<<dim3(250), 512, 0, stream>>>(Wfc, hgp, bfc, out);
}